// Round 15
// baseline (363.948 us; speedup 1.0000x reference)
//
#include <hip/hip_runtime.h>
#include <hip/hip_bf16.h>

typedef unsigned char  u8;
typedef unsigned short u16;
typedef unsigned int   u32;
typedef unsigned long long u64;
typedef signed char i8;
typedef __attribute__((ext_vector_type(8))) short s16x8;
typedef __attribute__((ext_vector_type(4))) int   i32x4;

#define NNODES 50000
#define PADM   50176          // 256 * 196, multiple of 128 and 16

#define GAS __attribute__((address_space(1)))
#define LAS __attribute__((address_space(3)))

// ---------------- fused setup: 4 weight quants + cnt zeroing ----------------
// x[row][K] f32 -> q = round(x*32256/rowmax) i16 -> qh=(q+128)>>8, ql=q-256*qh
// planes: qp[row][2K] i8 = [hi(K)|lo(K)]; ds[row] = rowmax/32256.

template <int K>
__device__ __forceinline__ void quant_rows_dev(
    const float* __restrict__ x, i8* __restrict__ qp, float* __restrict__ ds,
    int nrows, int blk0)
{
    constexpr int V = K / 64;    // 2, 4, 8
    const int wave = threadIdx.x >> 6, lane = threadIdx.x & 63;
    const int row = (blockIdx.x - blk0) * 4 + wave;
    if (row >= nrows) return;
    const float* xr = x + (size_t)row * K + lane * V;
    float v[V];
#pragma unroll
    for (int i = 0; i < V; i += 4) {
        if constexpr (V >= 4) {
            float4 t = *(const float4*)(xr + i);
            v[i] = t.x; v[i + 1] = t.y; v[i + 2] = t.z; v[i + 3] = t.w;
        }
    }
    if constexpr (V == 2) { float2 t = *(const float2*)xr; v[0] = t.x; v[1] = t.y; }
    float m = 0.f;
#pragma unroll
    for (int i = 0; i < V; ++i) m = fmaxf(m, fabsf(v[i]));
#pragma unroll
    for (int d = 32; d >= 1; d >>= 1) m = fmaxf(m, __shfl_xor(m, d));
    float inv = (m > 0.f) ? 32256.f / m : 0.f;
    if (lane == 0) ds[row] = (m > 0.f) ? m * (1.f / 32256.f) : 0.f;
    u64 hw = 0, lw = 0;
#pragma unroll
    for (int i = 0; i < V; ++i) {
        int q = __float2int_rn(v[i] * inv);
        int qh = (q + 128) >> 8;
        int ql = q - (qh << 8);
        hw |= (u64)(u8)qh << (8 * (i & 7));
        lw |= (u64)(u8)ql << (8 * (i & 7));
    }
    i8* o = qp + (size_t)row * (2 * K) + lane * V;
    if constexpr (V == 2) { *(u16*)o = (u16)hw; *(u16*)(o + K) = (u16)lw; }
    else if constexpr (V == 4) { *(u32*)o = (u32)hw; *(u32*)(o + K) = (u32)lw; }
    else { *(u64*)o = hw; *(u64*)(o + K) = lw; }
}

// grid = 32 + 64 + 128 + 256 + 196 = 676 blocks of 256
__global__ __launch_bounds__(256) void k_setup(
    const float* __restrict__ W1, i8* __restrict__ W1q, float* __restrict__ dsW1,
    const float* __restrict__ W2, i8* __restrict__ W2q, float* __restrict__ dsW2,
    const float* __restrict__ W3, i8* __restrict__ W3q, float* __restrict__ dsW3,
    const float* __restrict__ Wfc, i8* __restrict__ Wfcq, float* __restrict__ dsWfc,
    int* __restrict__ cnt, int nv)
{
    const int b = blockIdx.x;
    if (b < 32)        quant_rows_dev<128>(W1, W1q, dsW1, 128, 0);
    else if (b < 96)   quant_rows_dev<128>(W2, W2q, dsW2, 256, 32);
    else if (b < 224)  quant_rows_dev<256>(W3, W3q, dsW3, 512, 96);
    else if (b < 480)  quant_rows_dev<512>(Wfc, Wfcq, dsWfc, 1024, 224);
    else {
        int i = (b - 480) * 256 + threadIdx.x;
        if (i < nv) cnt[i] = 0;
    }
}

// ---------------- CSR build ----------------

__global__ void k_count(const int* __restrict__ dst, int E, int* __restrict__ cnt) {
    int e = blockIdx.x * 256 + threadIdx.x;
    if (e < E) atomicAdd(&cnt[dst[e]], 1);
}

// ---- parallel 3-pass scan ----

__global__ __launch_bounds__(256) void k_scan1(
    const int* __restrict__ cnt, float* __restrict__ dinv, int n, int* __restrict__ bsum)
{
    __shared__ int wsum[4];
    int i = blockIdx.x * 256 + threadIdx.x;
    int c = 0;
    if (i < n) {
        c = cnt[i];
        dinv[i] = rsqrtf((float)(c + 1));   // +1 self loop
    }
    int s = c;
#pragma unroll
    for (int d = 1; d < 64; d <<= 1) s += __shfl_xor(s, d);
    if ((threadIdx.x & 63) == 0) wsum[threadIdx.x >> 6] = s;
    __syncthreads();
    if (threadIdx.x == 0) bsum[blockIdx.x] = wsum[0] + wsum[1] + wsum[2] + wsum[3];
}

__global__ __launch_bounds__(256) void k_scan2(
    int* __restrict__ bsum, int nb, int* __restrict__ offs, int n)
{
    __shared__ int sh[256];
    int t = threadIdx.x;
    int v = (t < nb) ? bsum[t] : 0;
    sh[t] = v;
    __syncthreads();
#pragma unroll
    for (int d = 1; d < 256; d <<= 1) {
        int u = (t >= d) ? sh[t - d] : 0;
        __syncthreads();
        sh[t] += u;
        __syncthreads();
    }
    if (t < nb) bsum[t] = sh[t] - v;       // exclusive prefix
    if (t == 255) offs[n] = sh[nb - 1];    // total
}

__global__ __launch_bounds__(256) void k_scan3(
    const int* __restrict__ cnt, const int* __restrict__ bsum, int n,
    int* __restrict__ offs, int* __restrict__ cursor)
{
    __shared__ int sh[256];
    int t = threadIdx.x;
    int i = blockIdx.x * 256 + t;
    int c = (i < n) ? cnt[i] : 0;
    sh[t] = c;
    __syncthreads();
#pragma unroll
    for (int d = 1; d < 256; d <<= 1) {
        int u = (t >= d) ? sh[t - d] : 0;
        __syncthreads();
        sh[t] += u;
        __syncthreads();
    }
    if (i < n) {
        int excl = bsum[blockIdx.x] + sh[t] - c;
        offs[i] = excl;
        cursor[i] = excl;
    }
}

// fill packed CSR: (src, weight) as one int2 per edge — one 8B scattered store
__global__ void k_fill(const int* __restrict__ src, const int* __restrict__ dst, int E,
                       int* __restrict__ cursor, const float* __restrict__ dinv,
                       int2* __restrict__ csr_pk) {
    int e = blockIdx.x * 256 + threadIdx.x;
    if (e < E) {
        int s = src[e], d = dst[e];
        int slot = atomicAdd(&cursor[d], 1);
        int2 pk;
        pk.x = s;
        pk.y = __float_as_int(dinv[s] * dinv[d]);
        csr_pk[slot] = pk;
    }
}

// ---------------- standalone i8-split quant (FC input) ----------------

template <int K>
__global__ __launch_bounds__(256) void k_quant_i8(
    const float* __restrict__ x, i8* __restrict__ qp, float* __restrict__ ds, int nrows)
{
    quant_rows_dev<K>(x, qp, ds, nrows, 0);
}

// ---------------- per-row i16 quantization (layer-1 gather input only) ----------------

template <int C>
__global__ __launch_bounds__(256) void k_rowquant(
    const float* __restrict__ x, short* __restrict__ qo, float* __restrict__ ds, int nrows)
{
    constexpr int V = C / 64;
    const int wave = threadIdx.x >> 6, lane = threadIdx.x & 63;
    const int row = blockIdx.x * 4 + wave;
    if (row >= nrows) return;
    const float* xr = x + (size_t)row * C + lane * V;
    float v[V];
    if (V == 2) { float2 t = *(const float2*)xr; v[0] = t.x; v[1] = t.y; }
    else        { float4 t = *(const float4*)xr; v[0] = t.x; v[1] = t.y; v[2] = t.z; v[3] = t.w; }
    float m = 0.f;
#pragma unroll
    for (int i = 0; i < V; ++i) m = fmaxf(m, fabsf(v[i]));
#pragma unroll
    for (int d = 32; d >= 1; d >>= 1) m = fmaxf(m, __shfl_xor(m, d));
    float inv = (m > 0.f) ? 32767.f / m : 0.f;
    if (lane == 0) ds[row] = (m > 0.f) ? m * (1.f / 32767.f) : 0.f;
    short* qr = qo + (size_t)row * C + lane * V;
    if (V == 2) {
        u32 wd = (u32)(u16)(short)__float2int_rn(v[0] * inv)
               | ((u32)(u16)(short)__float2int_rn(v[1] * inv) << 16);
        *(u32*)qr = wd;
    } else {
        u64 wd = 0;
#pragma unroll
        for (int i = 0; i < 4; ++i)
            wd |= (u64)(u16)(short)__float2int_rn(v[i] * inv) << (16 * i);
        *(u64*)qr = wd;
    }
}

// ---------------- aggregation over i16 rows + fused i8-split output ----------------
// Scales: NS per row (one per 128-col chunk): ds[row*NS + k].

template <int C>   // 128 or 256
__global__ __launch_bounds__(256) void k_agg_q(
    const short* __restrict__ q, const float* __restrict__ ds,
    const int* __restrict__ offs, const int2* __restrict__ csr_pk,
    const float* __restrict__ dinv,
    i8* __restrict__ outp,         // [PADM][2C] i8 [hi(C)|lo(C)], pad rows zeroed
    float* __restrict__ dsA,       // [PADM]
    int nvalid, int padm)
{
    constexpr int NS = C / 128;     // short8 chunks per lane AND scales per row (1 or 2)
    const int sub = threadIdx.x >> 4;   // 0..15
    const int l = threadIdx.x & 15;
    const int node = blockIdx.x * 16 + sub;
    if (node >= padm) return;

    float acc[8 * NS];
#pragma unroll
    for (int i = 0; i < 8 * NS; ++i) acc[i] = 0.f;

    if (node < nvalid) {
        float di = dinv[node];
        float dd = di * di;
        float c0[NS];
        if (NS == 1) c0[0] = dd * ds[node];
        else { float2 t = *(const float2*)(ds + 2 * node); c0[0] = dd * t.x; c0[1] = dd * t.y; }
        const short* qn = q + (size_t)node * C + l * 8;
#pragma unroll
        for (int k = 0; k < NS; ++k) {
            s16x8 h = *(const s16x8*)(qn + k * 128);
#pragma unroll
            for (int i = 0; i < 8; ++i) acc[k * 8 + i] = c0[k] * (float)h[i];
        }

        int j0 = offs[node], j1 = offs[node + 1];
        int j = j0;
        for (; j + 4 <= j1; j += 4) {
            int2 p0 = csr_pk[j],     p1 = csr_pk[j + 1];
            int2 p2 = csr_pk[j + 2], p3 = csr_pk[j + 3];
            int s0 = p0.x, s1 = p1.x, s2 = p2.x, s3 = p3.x;
            float c0e[NS], c1e[NS], c2e[NS], c3e[NS];
            if (NS == 1) {
                c0e[0] = __int_as_float(p0.y) * ds[s0];
                c1e[0] = __int_as_float(p1.y) * ds[s1];
                c2e[0] = __int_as_float(p2.y) * ds[s2];
                c3e[0] = __int_as_float(p3.y) * ds[s3];
            } else {
                float2 t0 = *(const float2*)(ds + 2 * s0);
                float2 t1 = *(const float2*)(ds + 2 * s1);
                float2 t2 = *(const float2*)(ds + 2 * s2);
                float2 t3 = *(const float2*)(ds + 2 * s3);
                float w0 = __int_as_float(p0.y), w1 = __int_as_float(p1.y);
                float w2 = __int_as_float(p2.y), w3 = __int_as_float(p3.y);
                c0e[0] = w0 * t0.x; c0e[1] = w0 * t0.y;
                c1e[0] = w1 * t1.x; c1e[1] = w1 * t1.y;
                c2e[0] = w2 * t2.x; c2e[1] = w2 * t2.y;
                c3e[0] = w3 * t3.x; c3e[1] = w3 * t3.y;
            }
            const short* r0 = q + (size_t)s0 * C + l * 8;
            const short* r1 = q + (size_t)s1 * C + l * 8;
            const short* r2 = q + (size_t)s2 * C + l * 8;
            const short* r3 = q + (size_t)s3 * C + l * 8;
#pragma unroll
            for (int k = 0; k < NS; ++k) {
                s16x8 h0 = *(const s16x8*)(r0 + k * 128);
                s16x8 h1 = *(const s16x8*)(r1 + k * 128);
                s16x8 h2 = *(const s16x8*)(r2 + k * 128);
                s16x8 h3 = *(const s16x8*)(r3 + k * 128);
#pragma unroll
                for (int i = 0; i < 8; ++i) {
                    acc[k * 8 + i] = fmaf(c0e[k], (float)h0[i], acc[k * 8 + i]);
                    acc[k * 8 + i] = fmaf(c1e[k], (float)h1[i], acc[k * 8 + i]);
                    acc[k * 8 + i] = fmaf(c2e[k], (float)h2[i], acc[k * 8 + i]);
                    acc[k * 8 + i] = fmaf(c3e[k], (float)h3[i], acc[k * 8 + i]);
                }
            }
        }
        for (; j < j1; ++j) {
            int2 p0 = csr_pk[j];
            int s0 = p0.x;
            float w0 = __int_as_float(p0.y);
            float c0e[NS];
            if (NS == 1) c0e[0] = w0 * ds[s0];
            else { float2 t0 = *(const float2*)(ds + 2 * s0); c0e[0] = w0 * t0.x; c0e[1] = w0 * t0.y; }
            const short* r0 = q + (size_t)s0 * C + l * 8;
#pragma unroll
            for (int k = 0; k < NS; ++k) {
                s16x8 h0 = *(const s16x8*)(r0 + k * 128);
#pragma unroll
                for (int i = 0; i < 8; ++i)
                    acc[k * 8 + i] = fmaf(c0e[k], (float)h0[i], acc[k * 8 + i]);
            }
        }
    }

    // fused i8-split quant: rowmax over the 16-lane group, then planes
    float m = 0.f;
#pragma unroll
    for (int i = 0; i < 8 * NS; ++i) m = fmaxf(m, fabsf(acc[i]));
#pragma unroll
    for (int d = 8; d >= 1; d >>= 1) m = fmaxf(m, __shfl_xor(m, d));
    float inv = (m > 0.f) ? 32256.f / m : 0.f;
    if (l == 0) dsA[node] = (m > 0.f) ? m * (1.f / 32256.f) : 0.f;

    i8* po = outp + (size_t)node * (2 * C);
#pragma unroll
    for (int k = 0; k < NS; ++k) {
        u64 hw = 0, lw = 0;
#pragma unroll
        for (int i = 0; i < 8; ++i) {
            int qv = __float2int_rn(acc[k * 8 + i] * inv);
            int qh = (qv + 128) >> 8;
            int ql = qv - (qh << 8);
            hw |= (u64)(u8)qh << (8 * i);
            lw |= (u64)(u8)ql << (8 * i);
        }
        int col = l * 8 + k * 128;
        *(u64*)(po + col) = hw;
        *(u64*)(po + C + col) = lw;
    }
}

// ---------------- 128-tile i8 MFMA GEMM, 2-phase dbuf, 8 waves, 16x16x64 ----------------
// A [M][2K] i8 [hi|lo], W [N][2K] i8 [hi|lo];  x = dsA*(256*Ah + Al), w = dsW*(256*Wh + Wl)
// acc1 = Ah*Wh, acc2 = Ah*Wl + Al*Wh (i32, exact); Al*Wl dropped (~1e-4 stat).
// out = dsA[r]*dsW[c]*(65536*acc1 + 256*acc2) + bias.
// EPI: 0 = relu f32, all rows
//      1 = relu + fused i16 block-col quant -> Qo16[M][N] + dsO[M*nby]  (each block
//          owns 128 cols of its 128 rows; scale is per (row, 128-col chunk))
//      2 = f32 nontemporal, row < Mvalid

template <int EPI>
__global__ __launch_bounds__(512, 2) void k_gemm_i8(
    const i8* __restrict__ A2,
    const i8* __restrict__ W2,
    const float* __restrict__ dsA,
    const float* __restrict__ dsW,
    const float* __restrict__ bias,
    float* __restrict__ Cf,
    short* __restrict__ Qo16,
    float* __restrict__ dsO,
    int N, int K, int Mvalid, int nby)
{
    __shared__ i8 At[2][128 * 128];   // [row][ hi64 | lo64 ] per 64-k tile, XOR-swizzled
    __shared__ i8 Bt[2][128 * 128];
    __shared__ float shmax[4][128];   // EPI==1 cross-wave rowmax (2 KB)

    const int nwg = gridDim.x;
    const int orig = blockIdx.x;
    const int q8 = nwg >> 3, r8 = nwg & 7;
    const int xcd = orig & 7, slot = orig >> 3;
    const int L = (xcd < r8 ? xcd * (q8 + 1) : r8 * (q8 + 1) + (xcd - r8) * q8) + slot;
    const int by = L % nby;
    const int bx = L / nby;
    const int bm0 = bx * 128;
    const int bn0 = by * 128;
    const int tid = threadIdx.x;
    const int lane = tid & 63;
    const int w = tid >> 6;           // 0..7
    const int wr = w >> 2;            // 0..1  (64-row half)
    const int wc = w & 3;             // 0..3  (32-col quarter)
    const int g = lane >> 4, rl = lane & 15;
    const int K2 = 2 * K;
    const int NTK = K >> 6;           // 64-k tiles

    i32x4 acc1[4][2], acc2[4][2];
#pragma unroll
    for (int i = 0; i < 4; ++i)
#pragma unroll
        for (int j = 0; j < 2; ++j) {
            acc1[i][j][0] = 0; acc1[i][j][1] = 0; acc1[i][j][2] = 0; acc1[i][j][3] = 0;
            acc2[i][j][0] = 0; acc2[i][j][1] = 0; acc2[i][j][2] = 0; acc2[i][j][3] = 0;
        }

    // staging: linear LDS dest, inverse-swizzled global source (byte granularity)
    size_t aoff[2], boff[2];
    int ldsb[2];
#pragma unroll
    for (int r = 0; r < 2; ++r) {
        int a = r * 8192 + tid * 16;        // byte in 16KB tile
        int row = a >> 7;                   // 128 B per row
        int c = a & 127;
        int cs = c ^ ((row & 7) << 4);      // logical byte col in row
        int ce = (cs < 64) ? cs : (K + (cs - 64));   // plane offset (bytes)
        aoff[r] = (size_t)(bm0 + row) * K2 + ce;
        boff[r] = (size_t)(bn0 + row) * K2 + ce;
        ldsb[r] = a;
    }

#define STAGE_I8(buf, kk)                                                        \
    do {                                                                         \
        _Pragma("unroll")                                                        \
        for (int r = 0; r < 2; ++r) {                                            \
            __builtin_amdgcn_global_load_lds(                                    \
                (const GAS void*)(A2 + aoff[r] + (kk)),                          \
                (LAS void*)(&At[buf][0] + ldsb[r]), 16, 0, 0);                   \
            __builtin_amdgcn_global_load_lds(                                    \
                (const GAS void*)(W2 + boff[r] + (kk)),                          \
                (LAS void*)(&Bt[buf][0] + ldsb[r]), 16, 0, 0);                   \
        }                                                                        \
    } while (0)

    // prologue: stage tile 0 -> buf 0 (syncthreads drains vmcnt)
    STAGE_I8(0, 0);
    __syncthreads();

    for (int t = 0; t < NTK; ++t) {
        const int cur = t & 1;
        if (t + 1 < NTK) STAGE_I8(cur ^ 1, (t + 1) * 64);   // prefetch next tile

        i32x4 ah[4], al[4];
#pragma unroll
        for (int m = 0; m < 4; ++m) {
            int row = wr * 64 + m * 16 + rl;
            int sw = (row & 7) << 4;
            const i8* base = &At[cur][0] + row * 128;
            ah[m] = *(const i32x4*)(base + ((g * 16) ^ sw));
            al[m] = *(const i32x4*)(base + ((64 + g * 16) ^ sw));
        }
#pragma unroll
        for (int n = 0; n < 2; ++n) {
            int row = wc * 32 + n * 16 + rl;
            int sw = (row & 7) << 4;
            const i8* base = &Bt[cur][0] + row * 128;
            i32x4 bh = *(const i32x4*)(base + ((g * 16) ^ sw));
            i32x4 bl = *(const i32x4*)(base + ((64 + g * 16) ^ sw));
#pragma unroll
            for (int m = 0; m < 4; ++m) {
                acc1[m][n] = __builtin_amdgcn_mfma_i32_16x16x64_i8(ah[m], bh, acc1[m][n], 0, 0, 0);
                acc2[m][n] = __builtin_amdgcn_mfma_i32_16x16x64_i8(al[m], bh, acc2[m][n], 0, 0, 0);
                acc2[m][n] = __builtin_amdgcn_mfma_i32_16x16x64_i8(ah[m], bl, acc2[m][n], 0, 0, 0);
            }
        }
        __syncthreads();
    }

    // epilogue: C/D layout col = lane&15, row = (lane>>4)*4 + reg (dtype-independent)
    float sa[4][4];
#pragma unroll
    for (int m = 0; m < 4; ++m) {
        int row0 = bm0 + wr * 64 + m * 16 + g * 4;
#pragma unroll
        for (int qq = 0; qq < 4; ++qq) sa[m][qq] = dsA[row0 + qq];
    }

    if (EPI == 1) {
        // dequant + relu into regs; per-(row, 128-col-block) max
        float vv[4][2][4];
        float pm[4][4];
#pragma unroll
        for (int m = 0; m < 4; ++m)
#pragma unroll
            for (int qq = 0; qq < 4; ++qq) pm[m][qq] = 0.f;
#pragma unroll
        for (int n = 0; n < 2; ++n) {
            int colg = bn0 + wc * 32 + n * 16 + rl;
            float sw_ = dsW[colg];
            float bv = bias[colg];
#pragma unroll
            for (int m = 0; m < 4; ++m)
#pragma unroll
                for (int qq = 0; qq < 4; ++qq) {
                    float v = sa[m][qq] * sw_ *
                              (65536.f * (float)acc1[m][n][qq] + 256.f * (float)acc2[m][n][qq]) + bv;
                    v = fmaxf(v, 0.f);
                    vv[m][n][qq] = v;
                    pm[m][qq] = fmaxf(pm[m][qq], v);
                }
        }
        // reduce across the 16-lane rl group (stays within g-group: xor d<16)
#pragma unroll
        for (int d = 1; d < 16; d <<= 1)
#pragma unroll
            for (int m = 0; m < 4; ++m)
#pragma unroll
                for (int qq = 0; qq < 4; ++qq)
                    pm[m][qq] = fmaxf(pm[m][qq], __shfl_xor(pm[m][qq], d));
        // cross-wave (wc quarters) via LDS
        if (rl == 0) {
#pragma unroll
            for (int m = 0; m < 4; ++m)
#pragma unroll
                for (int qq = 0; qq < 4; ++qq)
                    shmax[wc][wr * 64 + m * 16 + g * 4 + qq] = pm[m][qq];
        }
        __syncthreads();
#pragma unroll
        for (int m = 0; m < 4; ++m)
#pragma unroll
            for (int qq = 0; qq < 4; ++qq) {
                int r = wr * 64 + m * 16 + g * 4 + qq;
                float rm = fmaxf(fmaxf(shmax[0][r], shmax[1][r]),
                                 fmaxf(shmax[2][r], shmax[3][r]));
                float invq = (rm > 0.f) ? 32767.f / rm : 0.f;
                if (wc == 0 && rl == 0)
                    dsO[(size_t)(bm0 + r) * nby + by] = (rm > 0.f) ? rm * (1.f / 32767.f) : 0.f;
#pragma unroll
                for (int n = 0; n < 2; ++n) {
                    int colg = bn0 + wc * 32 + n * 16 + rl;
                    Qo16[(size_t)(bm0 + r) * N + colg] =
                        (short)__float2int_rn(vv[m][n][qq] * invq);
                }
            }
        return;
    }

#pragma unroll
    for (int n = 0; n < 2; ++n) {
        int col = bn0 + wc * 32 + n * 16 + rl;
        float sw_ = dsW[col];
        float bv = bias[col];
#pragma unroll
        for (int m = 0; m < 4; ++m) {
            int row0 = bm0 + wr * 64 + m * 16 + g * 4;
#pragma unroll
            for (int qq = 0; qq < 4; ++qq) {
                int row = row0 + qq;
                float v = sa[m][qq] * sw_ *
                          (65536.f * (float)acc1[m][n][qq] + 256.f * (float)acc2[m][n][qq]) + bv;
                if (EPI == 0) {
                    Cf[(size_t)row * N + col] = fmaxf(v, 0.f);
                } else {
                    if (row < Mvalid)
                        __builtin_nontemporal_store(v, &Cf[(size_t)row * N + col]);
                }
            }
        }
    }
#undef STAGE_I8
}

// ---------------- launch ----------------

static inline size_t align_up(size_t x, size_t a) { return (x + a - 1) & ~(a - 1); }

extern "C" void kernel_launch(void* const* d_in, const int* in_sizes, int n_in,
                              void* d_out, int out_size, void* d_ws, size_t ws_size,
                              hipStream_t stream) {
    const int*   edge_index = (const int*)d_in[0];
    const float* node = (const float*)d_in[1];
    const float* W1 = (const float*)d_in[2];
    const float* b1 = (const float*)d_in[3];
    const float* W2 = (const float*)d_in[4];
    const float* b2 = (const float*)d_in[5];
    const float* W3 = (const float*)d_in[6];
    const float* b3 = (const float*)d_in[7];
    const float* Wfc = (const float*)d_in[8];
    const float* bfc = (const float*)d_in[9];
    float* out = (float*)d_out;

    const int E = in_sizes[0] / 2;   // 400000
    const int NV = NNODES;
    const int P = PADM;
    const int NB = (NV + 255) / 256;   // 196 scan chunks

    // workspace layout
    char* ws = (char*)d_ws;
    size_t off = 0;
    int* cnt = (int*)(ws + off);          off = align_up(off + (size_t)NV * 4, 1024);
    int* offs = (int*)(ws + off);         off = align_up(off + (size_t)(NV + 1) * 4, 1024);
    int* cursor = (int*)(ws + off);       off = align_up(off + (size_t)NV * 4, 1024);
    int* bsum = (int*)(ws + off);         off = align_up(off + (size_t)NB * 4, 1024);
    float* dinv = (float*)(ws + off);     off = align_up(off + (size_t)NV * 4, 1024);
    int2* csr_pk = (int2*)(ws + off);     off = align_up(off + (size_t)E * 8, 1024);
    i8* W1q = (i8*)(ws + off);            off = align_up(off + (size_t)128 * 256, 1024);
    i8* W2q = (i8*)(ws + off);            off = align_up(off + (size_t)256 * 256, 1024);
    i8* W3q = (i8*)(ws + off);            off = align_up(off + (size_t)512 * 512, 1024);
    i8* Wfcq = (i8*)(ws + off);           off = align_up(off + (size_t)1024 * 1024, 1024);
    float* dsW1 = (float*)(ws + off);     off = align_up(off + 128 * 4, 1024);
    float* dsW2 = (float*)(ws + off);     off = align_up(off + 256 * 4, 1024);
    float* dsW3 = (float*)(ws + off);     off = align_up(off + 512 * 4, 1024);
    float* dsWfc = (float*)(ws + off);    off = align_up(off + 1024 * 4, 1024);
    float* dsQ = (float*)(ws + off);      off = align_up(off + (size_t)P * 4, 1024);
    float* ds2 = (float*)(ws + off);      off = align_up(off + (size_t)P * 8, 1024);
    float* dsAgg = (float*)(ws + off);    off = align_up(off + (size_t)P * 4, 1024);
    float* dsAfc = (float*)(ws + off);    off = align_up(off + (size_t)P * 4, 1024);
    i8* A3q = (i8*)(ws + off);            off = align_up(off + (size_t)P * 512, 1024);
    i8* A4q = (i8*)(ws + off);            off = align_up(off + (size_t)P * 1024, 1024);
    // BIG overlapped region (P*2048 bytes): xbuf3 aliases {q01, A1q, q2},
    // all of which are dead by the time layer-3 GEMM writes xbuf3.
    char* big = ws + off;                 off = align_up(off + (size_t)P * 2048, 1024);
    short* q01 = (short*)big;                          // P*128 i16 = P*256 B
    i8* A1q = (i8*)(big + (size_t)P * 256);            // P*256 B
    short* q2 = (short*)(big + (size_t)P * 512);       // P*256 i16 = P*512 B
    float* xbuf3 = (float*)big;                        // P*512 f32 = P*2048 B

    const int* src = edge_index;
    const int* dst = edge_index + E;

    // setup: 4 weight quants + cnt zeroing (one launch)
    k_setup<<<676, 256, 0, stream>>>(W1, W1q, dsW1, W2, W2q, dsW2, W3, W3q, dsW3,
                                     Wfc, Wfcq, dsWfc, cnt, NV);

    // CSR build (parallel scan)
    k_count<<<(E + 255) / 256, 256, 0, stream>>>(dst, E, cnt);
    k_scan1<<<NB, 256, 0, stream>>>(cnt, dinv, NV, bsum);
    k_scan2<<<1, 256, 0, stream>>>(bsum, NB, offs, NV);
    k_scan3<<<NB, 256, 0, stream>>>(cnt, bsum, NV, offs, cursor);
    k_fill<<<(E + 255) / 256, 256, 0, stream>>>(src, dst, E, cursor, dinv, csr_pk);

    dim3 blk(256);
    dim3 blk512(512);
    const int qGrid = (NV + 3) / 4;    // rowquant: 4 rows/block
    const int aGrid = P / 16;          // agg: 16 nodes/block
    const int nbx = P / 128;           // 392

    // layer 1: quant(node) -> q01+dsQ, agg -> A1q+dsAgg,
    //          gemm EPI1 -> q01 i16 + dsQ (fused; no f32 intermediate)
    k_rowquant<128><<<qGrid, blk, 0, stream>>>(node, q01, dsQ, NV);
    k_agg_q<128><<<aGrid, blk, 0, stream>>>(q01, dsQ, offs, csr_pk, dinv, A1q, dsAgg, NV, P);
    k_gemm_i8<1><<<nbx * 1, blk512, 0, stream>>>(A1q, W1q, dsAgg, dsW1, b1,
                                                 nullptr, q01, dsQ, 128, 128, P, 1);

    // layer 2: agg -> A1q+dsAgg, gemm EPI1 (N=256, per-half scales) -> q2 + ds2
    k_agg_q<128><<<aGrid, blk, 0, stream>>>(q01, dsQ, offs, csr_pk, dinv, A1q, dsAgg, NV, P);
    k_gemm_i8<1><<<nbx * 2, blk512, 0, stream>>>(A1q, W2q, dsAgg, dsW2, b2,
                                                 nullptr, q2, ds2, 256, 128, P, 2);

    // layer 3: agg (NS=2 scales) -> A3q+dsAgg, gemm EPI0 -> xbuf3
    k_agg_q<256><<<aGrid, blk, 0, stream>>>(q2, ds2, offs, csr_pk, dinv, A3q, dsAgg, NV, P);
    k_gemm_i8<0><<<nbx * 4, blk512, 0, stream>>>(A3q, W3q, dsAgg, dsW3, b3,
                                                 xbuf3, nullptr, nullptr, 512, 256, P, 4);

    // FC: quantize xbuf3 rows -> A4q planes, then i8 gemm -> out (rows < NV)
    k_quant_i8<512><<<(P + 3) / 4, 256, 0, stream>>>(xbuf3, A4q, dsAfc, P);
    k_gemm_i8<2><<<nbx * 8, blk512, 0, stream>>>(A4q, Wfcq, dsAfc, dsWfc, bfc,
                                                 out, nullptr, nullptr, 1024, 512, NV, 8);
}

// Round 16
// 354.407 us; speedup vs baseline: 1.0269x; 1.0269x over previous
//
#include <hip/hip_runtime.h>
#include <hip/hip_bf16.h>

typedef unsigned char  u8;
typedef unsigned short u16;
typedef unsigned int   u32;
typedef unsigned long long u64;
typedef signed char i8;
typedef __attribute__((ext_vector_type(8))) short s16x8;
typedef __attribute__((ext_vector_type(4))) int   i32x4;

#define NNODES 50000
#define PADM   50176          // 256 * 196, multiple of 128 and 16

#define GAS __attribute__((address_space(1)))
#define LAS __attribute__((address_space(3)))

// ---------------- fused setup: 4 weight quants + cnt zeroing ----------------
// x[row][K] f32 -> q = round(x*32256/rowmax) i16 -> qh=(q+128)>>8, ql=q-256*qh
// planes: qp[row][2K] i8 = [hi(K)|lo(K)]; ds[row] = rowmax/32256.

template <int K>
__device__ __forceinline__ void quant_rows_dev(
    const float* __restrict__ x, i8* __restrict__ qp, float* __restrict__ ds,
    int nrows, int blk0)
{
    constexpr int V = K / 64;    // 2, 4, 8
    const int wave = threadIdx.x >> 6, lane = threadIdx.x & 63;
    const int row = (blockIdx.x - blk0) * 4 + wave;
    if (row >= nrows) return;
    const float* xr = x + (size_t)row * K + lane * V;
    float v[V];
#pragma unroll
    for (int i = 0; i < V; i += 4) {
        if constexpr (V >= 4) {
            float4 t = *(const float4*)(xr + i);
            v[i] = t.x; v[i + 1] = t.y; v[i + 2] = t.z; v[i + 3] = t.w;
        }
    }
    if constexpr (V == 2) { float2 t = *(const float2*)xr; v[0] = t.x; v[1] = t.y; }
    float m = 0.f;
#pragma unroll
    for (int i = 0; i < V; ++i) m = fmaxf(m, fabsf(v[i]));
#pragma unroll
    for (int d = 32; d >= 1; d >>= 1) m = fmaxf(m, __shfl_xor(m, d));
    float inv = (m > 0.f) ? 32256.f / m : 0.f;
    if (lane == 0) ds[row] = (m > 0.f) ? m * (1.f / 32256.f) : 0.f;
    u64 hw = 0, lw = 0;
#pragma unroll
    for (int i = 0; i < V; ++i) {
        int q = __float2int_rn(v[i] * inv);
        int qh = (q + 128) >> 8;
        int ql = q - (qh << 8);
        hw |= (u64)(u8)qh << (8 * (i & 7));
        lw |= (u64)(u8)ql << (8 * (i & 7));
    }
    i8* o = qp + (size_t)row * (2 * K) + lane * V;
    if constexpr (V == 2) { *(u16*)o = (u16)hw; *(u16*)(o + K) = (u16)lw; }
    else if constexpr (V == 4) { *(u32*)o = (u32)hw; *(u32*)(o + K) = (u32)lw; }
    else { *(u64*)o = hw; *(u64*)(o + K) = lw; }
}

// grid = 32 + 64 + 128 + 256 + 196 = 676 blocks of 256
__global__ __launch_bounds__(256) void k_setup(
    const float* __restrict__ W1, i8* __restrict__ W1q, float* __restrict__ dsW1,
    const float* __restrict__ W2, i8* __restrict__ W2q, float* __restrict__ dsW2,
    const float* __restrict__ W3, i8* __restrict__ W3q, float* __restrict__ dsW3,
    const float* __restrict__ Wfc, i8* __restrict__ Wfcq, float* __restrict__ dsWfc,
    int* __restrict__ cnt, int nv)
{
    const int b = blockIdx.x;
    if (b < 32)        quant_rows_dev<128>(W1, W1q, dsW1, 128, 0);
    else if (b < 96)   quant_rows_dev<128>(W2, W2q, dsW2, 256, 32);
    else if (b < 224)  quant_rows_dev<256>(W3, W3q, dsW3, 512, 96);
    else if (b < 480)  quant_rows_dev<512>(Wfc, Wfcq, dsWfc, 1024, 224);
    else {
        int i = (b - 480) * 256 + threadIdx.x;
        if (i < nv) cnt[i] = 0;
    }
}

// ---------------- CSR build ----------------

__global__ void k_count(const int* __restrict__ dst, int E, int* __restrict__ cnt) {
    int e = blockIdx.x * 256 + threadIdx.x;
    if (e < E) atomicAdd(&cnt[dst[e]], 1);
}

// ---- parallel 3-pass scan ----

__global__ __launch_bounds__(256) void k_scan1(
    const int* __restrict__ cnt, float* __restrict__ dinv, int n, int* __restrict__ bsum)
{
    __shared__ int wsum[4];
    int i = blockIdx.x * 256 + threadIdx.x;
    int c = 0;
    if (i < n) {
        c = cnt[i];
        dinv[i] = rsqrtf((float)(c + 1));   // +1 self loop
    }
    int s = c;
#pragma unroll
    for (int d = 1; d < 64; d <<= 1) s += __shfl_xor(s, d);
    if ((threadIdx.x & 63) == 0) wsum[threadIdx.x >> 6] = s;
    __syncthreads();
    if (threadIdx.x == 0) bsum[blockIdx.x] = wsum[0] + wsum[1] + wsum[2] + wsum[3];
}

__global__ __launch_bounds__(256) void k_scan2(
    int* __restrict__ bsum, int nb, int* __restrict__ offs, int n)
{
    __shared__ int sh[256];
    int t = threadIdx.x;
    int v = (t < nb) ? bsum[t] : 0;
    sh[t] = v;
    __syncthreads();
#pragma unroll
    for (int d = 1; d < 256; d <<= 1) {
        int u = (t >= d) ? sh[t - d] : 0;
        __syncthreads();
        sh[t] += u;
        __syncthreads();
    }
    if (t < nb) bsum[t] = sh[t] - v;       // exclusive prefix
    if (t == 255) offs[n] = sh[nb - 1];    // total
}

__global__ __launch_bounds__(256) void k_scan3(
    const int* __restrict__ cnt, const int* __restrict__ bsum, int n,
    int* __restrict__ offs, int* __restrict__ cursor)
{
    __shared__ int sh[256];
    int t = threadIdx.x;
    int i = blockIdx.x * 256 + t;
    int c = (i < n) ? cnt[i] : 0;
    sh[t] = c;
    __syncthreads();
#pragma unroll
    for (int d = 1; d < 256; d <<= 1) {
        int u = (t >= d) ? sh[t - d] : 0;
        __syncthreads();
        sh[t] += u;
        __syncthreads();
    }
    if (i < n) {
        int excl = bsum[blockIdx.x] + sh[t] - c;
        offs[i] = excl;
        cursor[i] = excl;
    }
}

// fill packed CSR: (src, weight) as one int2 per edge — one 8B scattered store
__global__ void k_fill(const int* __restrict__ src, const int* __restrict__ dst, int E,
                       int* __restrict__ cursor, const float* __restrict__ dinv,
                       int2* __restrict__ csr_pk) {
    int e = blockIdx.x * 256 + threadIdx.x;
    if (e < E) {
        int s = src[e], d = dst[e];
        int slot = atomicAdd(&cursor[d], 1);
        int2 pk;
        pk.x = s;
        pk.y = __float_as_int(dinv[s] * dinv[d]);
        csr_pk[slot] = pk;
    }
}

// ---------------- standalone i8-split quant (FC input) ----------------

template <int K>
__global__ __launch_bounds__(256) void k_quant_i8(
    const float* __restrict__ x, i8* __restrict__ qp, float* __restrict__ ds, int nrows)
{
    quant_rows_dev<K>(x, qp, ds, nrows, 0);
}

// ---------------- per-row i16 quantization (agg gather input) ----------------

template <int C>   // 128 or 256
__global__ __launch_bounds__(256) void k_rowquant(
    const float* __restrict__ x, short* __restrict__ qo, float* __restrict__ ds, int nrows)
{
    constexpr int V = C / 64;
    const int wave = threadIdx.x >> 6, lane = threadIdx.x & 63;
    const int row = blockIdx.x * 4 + wave;
    if (row >= nrows) return;
    const float* xr = x + (size_t)row * C + lane * V;
    float v[V];
    if (V == 2) { float2 t = *(const float2*)xr; v[0] = t.x; v[1] = t.y; }
    else        { float4 t = *(const float4*)xr; v[0] = t.x; v[1] = t.y; v[2] = t.z; v[3] = t.w; }
    float m = 0.f;
#pragma unroll
    for (int i = 0; i < V; ++i) m = fmaxf(m, fabsf(v[i]));
#pragma unroll
    for (int d = 32; d >= 1; d >>= 1) m = fmaxf(m, __shfl_xor(m, d));
    float inv = (m > 0.f) ? 32767.f / m : 0.f;
    if (lane == 0) ds[row] = (m > 0.f) ? m * (1.f / 32767.f) : 0.f;
    short* qr = qo + (size_t)row * C + lane * V;
    if (V == 2) {
        u32 wd = (u32)(u16)(short)__float2int_rn(v[0] * inv)
               | ((u32)(u16)(short)__float2int_rn(v[1] * inv) << 16);
        *(u32*)qr = wd;
    } else {
        u64 wd = 0;
#pragma unroll
        for (int i = 0; i < 4; ++i)
            wd |= (u64)(u16)(short)__float2int_rn(v[i] * inv) << (16 * i);
        *(u64*)qr = wd;
    }
}

// ---------------- aggregation over i16 rows + fused i8-split output ----------------

template <int C>   // 128 or 256
__global__ __launch_bounds__(256) void k_agg_q(
    const short* __restrict__ q, const float* __restrict__ ds,
    const int* __restrict__ offs, const int2* __restrict__ csr_pk,
    const float* __restrict__ dinv,
    i8* __restrict__ outp,         // [PADM][2C] i8 [hi(C)|lo(C)], pad rows zeroed
    float* __restrict__ dsA,       // [PADM]
    int nvalid, int padm)
{
    constexpr int NS = C / 128;     // short8 chunks per lane (1 or 2)
    const int sub = threadIdx.x >> 4;   // 0..15
    const int l = threadIdx.x & 15;
    const int node = blockIdx.x * 16 + sub;
    if (node >= padm) return;

    float acc[8 * NS];
#pragma unroll
    for (int i = 0; i < 8 * NS; ++i) acc[i] = 0.f;

    if (node < nvalid) {
        float di = dinv[node];
        float c0 = di * di * ds[node];
        const short* qn = q + (size_t)node * C + l * 8;
#pragma unroll
        for (int k = 0; k < NS; ++k) {
            s16x8 h = *(const s16x8*)(qn + k * 128);
#pragma unroll
            for (int i = 0; i < 8; ++i) acc[k * 8 + i] = c0 * (float)h[i];
        }

        int j0 = offs[node], j1 = offs[node + 1];
        int j = j0;
        for (; j + 4 <= j1; j += 4) {
            int2 p0 = csr_pk[j],     p1 = csr_pk[j + 1];
            int2 p2 = csr_pk[j + 2], p3 = csr_pk[j + 3];
            int s0 = p0.x, s1 = p1.x, s2 = p2.x, s3 = p3.x;
            float c0e = __int_as_float(p0.y) * ds[s0];
            float c1e = __int_as_float(p1.y) * ds[s1];
            float c2e = __int_as_float(p2.y) * ds[s2];
            float c3e = __int_as_float(p3.y) * ds[s3];
            const short* r0 = q + (size_t)s0 * C + l * 8;
            const short* r1 = q + (size_t)s1 * C + l * 8;
            const short* r2 = q + (size_t)s2 * C + l * 8;
            const short* r3 = q + (size_t)s3 * C + l * 8;
#pragma unroll
            for (int k = 0; k < NS; ++k) {
                s16x8 h0 = *(const s16x8*)(r0 + k * 128);
                s16x8 h1 = *(const s16x8*)(r1 + k * 128);
                s16x8 h2 = *(const s16x8*)(r2 + k * 128);
                s16x8 h3 = *(const s16x8*)(r3 + k * 128);
#pragma unroll
                for (int i = 0; i < 8; ++i) {
                    acc[k * 8 + i] = fmaf(c0e, (float)h0[i], acc[k * 8 + i]);
                    acc[k * 8 + i] = fmaf(c1e, (float)h1[i], acc[k * 8 + i]);
                    acc[k * 8 + i] = fmaf(c2e, (float)h2[i], acc[k * 8 + i]);
                    acc[k * 8 + i] = fmaf(c3e, (float)h3[i], acc[k * 8 + i]);
                }
            }
        }
        if (j + 2 <= j1) {
            int2 p0 = csr_pk[j], p1 = csr_pk[j + 1];
            int s0 = p0.x, s1 = p1.x;
            float c0e = __int_as_float(p0.y) * ds[s0];
            float c1e = __int_as_float(p1.y) * ds[s1];
            const short* r0 = q + (size_t)s0 * C + l * 8;
            const short* r1 = q + (size_t)s1 * C + l * 8;
#pragma unroll
            for (int k = 0; k < NS; ++k) {
                s16x8 h0 = *(const s16x8*)(r0 + k * 128);
                s16x8 h1 = *(const s16x8*)(r1 + k * 128);
#pragma unroll
                for (int i = 0; i < 8; ++i) {
                    acc[k * 8 + i] = fmaf(c0e, (float)h0[i], acc[k * 8 + i]);
                    acc[k * 8 + i] = fmaf(c1e, (float)h1[i], acc[k * 8 + i]);
                }
            }
            j += 2;
        }
        if (j < j1) {
            int2 p0 = csr_pk[j];
            int s0 = p0.x;
            float c0e = __int_as_float(p0.y) * ds[s0];
            const short* r0 = q + (size_t)s0 * C + l * 8;
#pragma unroll
            for (int k = 0; k < NS; ++k) {
                s16x8 h0 = *(const s16x8*)(r0 + k * 128);
#pragma unroll
                for (int i = 0; i < 8; ++i)
                    acc[k * 8 + i] = fmaf(c0e, (float)h0[i], acc[k * 8 + i]);
            }
        }
    }

    // fused i8-split quant: rowmax over the 16-lane group, then planes
    float m = 0.f;
#pragma unroll
    for (int i = 0; i < 8 * NS; ++i) m = fmaxf(m, fabsf(acc[i]));
#pragma unroll
    for (int d = 8; d >= 1; d >>= 1) m = fmaxf(m, __shfl_xor(m, d));
    float inv = (m > 0.f) ? 32256.f / m : 0.f;
    if (l == 0) dsA[node] = (m > 0.f) ? m * (1.f / 32256.f) : 0.f;

    i8* po = outp + (size_t)node * (2 * C);
#pragma unroll
    for (int k = 0; k < NS; ++k) {
        u64 hw = 0, lw = 0;
#pragma unroll
        for (int i = 0; i < 8; ++i) {
            int qv = __float2int_rn(acc[k * 8 + i] * inv);
            int qh = (qv + 128) >> 8;
            int ql = qv - (qh << 8);
            hw |= (u64)(u8)qh << (8 * i);
            lw |= (u64)(u8)ql << (8 * i);
        }
        int col = l * 8 + k * 128;
        *(u64*)(po + col) = hw;
        *(u64*)(po + C + col) = lw;
    }
}

// ---------------- 128-tile i8 MFMA GEMM, 2-phase dbuf, 8 waves, 16x16x64 ----------------
// (best-measured config: R13 @ 355 µs — 0 bank conflicts, VGPR fits 2 blocks/CU)
// A [M][2K] i8 [hi|lo], W [N][2K] i8 [hi|lo];  x = dsA*(256*Ah + Al), w = dsW*(256*Wh + Wl)
// acc1 = Ah*Wh, acc2 = Ah*Wl + Al*Wh (i32, exact); Al*Wl dropped (~1e-4 stat).
// out = dsA[r]*dsW[c]*(65536*acc1 + 256*acc2) + bias.
// EPI: 0 = relu f32, all rows; 2 = f32 nontemporal, row < Mvalid

template <int EPI>
__global__ __launch_bounds__(512, 2) void k_gemm_i8(
    const i8* __restrict__ A2,
    const i8* __restrict__ W2,
    const float* __restrict__ dsA,
    const float* __restrict__ dsW,
    const float* __restrict__ bias,
    float* __restrict__ Cf,
    int N, int K, int Mvalid, int nby)
{
    __shared__ i8 At[2][128 * 128];   // [row][ hi64 | lo64 ] per 64-k tile, XOR-swizzled
    __shared__ i8 Bt[2][128 * 128];

    const int nwg = gridDim.x;
    const int orig = blockIdx.x;
    const int q8 = nwg >> 3, r8 = nwg & 7;
    const int xcd = orig & 7, slot = orig >> 3;
    const int L = (xcd < r8 ? xcd * (q8 + 1) : r8 * (q8 + 1) + (xcd - r8) * q8) + slot;
    const int by = L % nby;
    const int bx = L / nby;
    const int bm0 = bx * 128;
    const int bn0 = by * 128;
    const int tid = threadIdx.x;
    const int lane = tid & 63;
    const int w = tid >> 6;           // 0..7
    const int wr = w >> 2;            // 0..1  (64-row half)
    const int wc = w & 3;             // 0..3  (32-col quarter)
    const int g = lane >> 4, rl = lane & 15;
    const int K2 = 2 * K;
    const int NTK = K >> 6;           // 64-k tiles

    i32x4 acc1[4][2], acc2[4][2];
#pragma unroll
    for (int i = 0; i < 4; ++i)
#pragma unroll
        for (int j = 0; j < 2; ++j) {
            acc1[i][j][0] = 0; acc1[i][j][1] = 0; acc1[i][j][2] = 0; acc1[i][j][3] = 0;
            acc2[i][j][0] = 0; acc2[i][j][1] = 0; acc2[i][j][2] = 0; acc2[i][j][3] = 0;
        }

    // staging: linear LDS dest, inverse-swizzled global source (byte granularity)
    // 512 threads x 16 B = 8 KB per issue; 2 issues cover a 16 KB operand tile.
    size_t aoff[2], boff[2];
    int ldsb[2];
#pragma unroll
    for (int r = 0; r < 2; ++r) {
        int a = r * 8192 + tid * 16;        // byte in 16KB tile
        int row = a >> 7;                   // 128 B per row
        int c = a & 127;
        int cs = c ^ ((row & 7) << 4);      // logical byte col in row
        int ce = (cs < 64) ? cs : (K + (cs - 64));   // plane offset (bytes)
        aoff[r] = (size_t)(bm0 + row) * K2 + ce;
        boff[r] = (size_t)(bn0 + row) * K2 + ce;
        ldsb[r] = a;
    }

#define STAGE_I8(buf, kk)                                                        \
    do {                                                                         \
        _Pragma("unroll")                                                        \
        for (int r = 0; r < 2; ++r) {                                            \
            __builtin_amdgcn_global_load_lds(                                    \
                (const GAS void*)(A2 + aoff[r] + (kk)),                          \
                (LAS void*)(&At[buf][0] + ldsb[r]), 16, 0, 0);                   \
            __builtin_amdgcn_global_load_lds(                                    \
                (const GAS void*)(W2 + boff[r] + (kk)),                          \
                (LAS void*)(&Bt[buf][0] + ldsb[r]), 16, 0, 0);                   \
        }                                                                        \
    } while (0)

    // prologue: stage tile 0 -> buf 0 (syncthreads drains vmcnt)
    STAGE_I8(0, 0);
    __syncthreads();

    for (int t = 0; t < NTK; ++t) {
        const int cur = t & 1;
        if (t + 1 < NTK) STAGE_I8(cur ^ 1, (t + 1) * 64);   // prefetch next tile

        i32x4 ah[4], al[4];
#pragma unroll
        for (int m = 0; m < 4; ++m) {
            int row = wr * 64 + m * 16 + rl;
            int sw = (row & 7) << 4;
            const i8* base = &At[cur][0] + row * 128;
            ah[m] = *(const i32x4*)(base + ((g * 16) ^ sw));
            al[m] = *(const i32x4*)(base + ((64 + g * 16) ^ sw));
        }
#pragma unroll
        for (int n = 0; n < 2; ++n) {
            int row = wc * 32 + n * 16 + rl;
            int sw = (row & 7) << 4;
            const i8* base = &Bt[cur][0] + row * 128;
            i32x4 bh = *(const i32x4*)(base + ((g * 16) ^ sw));
            i32x4 bl = *(const i32x4*)(base + ((64 + g * 16) ^ sw));
#pragma unroll
            for (int m = 0; m < 4; ++m) {
                acc1[m][n] = __builtin_amdgcn_mfma_i32_16x16x64_i8(ah[m], bh, acc1[m][n], 0, 0, 0);
                acc2[m][n] = __builtin_amdgcn_mfma_i32_16x16x64_i8(al[m], bh, acc2[m][n], 0, 0, 0);
                acc2[m][n] = __builtin_amdgcn_mfma_i32_16x16x64_i8(ah[m], bl, acc2[m][n], 0, 0, 0);
            }
        }
        __syncthreads();
    }

    // epilogue: C/D layout col = lane&15, row = (lane>>4)*4 + reg (dtype-independent)
    float sa[4][4];
#pragma unroll
    for (int m = 0; m < 4; ++m) {
        int row0 = bm0 + wr * 64 + m * 16 + g * 4;
#pragma unroll
        for (int qq = 0; qq < 4; ++qq) sa[m][qq] = dsA[row0 + qq];
    }
#pragma unroll
    for (int n = 0; n < 2; ++n) {
        int col = bn0 + wc * 32 + n * 16 + rl;
        float sw_ = dsW[col];
        float bv = bias[col];
#pragma unroll
        for (int m = 0; m < 4; ++m) {
            int row0 = bm0 + wr * 64 + m * 16 + g * 4;
#pragma unroll
            for (int qq = 0; qq < 4; ++qq) {
                int row = row0 + qq;
                float v = sa[m][qq] * sw_ *
                          (65536.f * (float)acc1[m][n][qq] + 256.f * (float)acc2[m][n][qq]) + bv;
                if (EPI == 0) {
                    Cf[(size_t)row * N + col] = fmaxf(v, 0.f);
                } else {
                    if (row < Mvalid)
                        __builtin_nontemporal_store(v, &Cf[(size_t)row * N + col]);
                }
            }
        }
    }
#undef STAGE_I8
}

// ---------------- launch ----------------

static inline size_t align_up(size_t x, size_t a) { return (x + a - 1) & ~(a - 1); }

extern "C" void kernel_launch(void* const* d_in, const int* in_sizes, int n_in,
                              void* d_out, int out_size, void* d_ws, size_t ws_size,
                              hipStream_t stream) {
    const int*   edge_index = (const int*)d_in[0];
    const float* node = (const float*)d_in[1];
    const float* W1 = (const float*)d_in[2];
    const float* b1 = (const float*)d_in[3];
    const float* W2 = (const float*)d_in[4];
    const float* b2 = (const float*)d_in[5];
    const float* W3 = (const float*)d_in[6];
    const float* b3 = (const float*)d_in[7];
    const float* Wfc = (const float*)d_in[8];
    const float* bfc = (const float*)d_in[9];
    float* out = (float*)d_out;

    const int E = in_sizes[0] / 2;   // 400000
    const int NV = NNODES;
    const int P = PADM;
    const int NB = (NV + 255) / 256;   // 196 scan chunks

    // workspace layout
    char* ws = (char*)d_ws;
    size_t off = 0;
    int* cnt = (int*)(ws + off);          off = align_up(off + (size_t)NV * 4, 1024);
    int* offs = (int*)(ws + off);         off = align_up(off + (size_t)(NV + 1) * 4, 1024);
    int* cursor = (int*)(ws + off);       off = align_up(off + (size_t)NV * 4, 1024);
    int* bsum = (int*)(ws + off);         off = align_up(off + (size_t)NB * 4, 1024);
    float* dinv = (float*)(ws + off);     off = align_up(off + (size_t)NV * 4, 1024);
    int2* csr_pk = (int2*)(ws + off);     off = align_up(off + (size_t)E * 8, 1024);
    i8* W1q = (i8*)(ws + off);            off = align_up(off + (size_t)128 * 256, 1024);
    i8* W2q = (i8*)(ws + off);            off = align_up(off + (size_t)256 * 256, 1024);
    i8* W3q = (i8*)(ws + off);            off = align_up(off + (size_t)512 * 512, 1024);
    i8* Wfcq = (i8*)(ws + off);           off = align_up(off + (size_t)1024 * 1024, 1024);
    float* dsW1 = (float*)(ws + off);     off = align_up(off + 128 * 4, 1024);
    float* dsW2 = (float*)(ws + off);     off = align_up(off + 256 * 4, 1024);
    float* dsW3 = (float*)(ws + off);     off = align_up(off + 512 * 4, 1024);
    float* dsWfc = (float*)(ws + off);    off = align_up(off + 1024 * 4, 1024);
    float* dsQ = (float*)(ws + off);      off = align_up(off + (size_t)P * 4, 1024);
    float* dsAgg = (float*)(ws + off);    off = align_up(off + (size_t)P * 4, 1024);
    float* dsAfc = (float*)(ws + off);    off = align_up(off + (size_t)P * 4, 1024);
    i8* A3q = (i8*)(ws + off);            off = align_up(off + (size_t)P * 512, 1024);
    i8* A4q = (i8*)(ws + off);            off = align_up(off + (size_t)P * 1024, 1024);
    // BIG overlapped region (P*2048 bytes): xbuf3 aliases {q01, A1q, xbuf1/q2, xbuf2},
    // all of which are dead by the time layer-3 GEMM writes xbuf3.
    char* big = ws + off;                 off = align_up(off + (size_t)P * 2048, 1024);
    short* q01 = (short*)big;                          // P*128 i16 = P*256 B
    i8* A1q = (i8*)(big + (size_t)P * 256);            // P*256 B
    float* xbuf1 = (float*)(big + (size_t)P * 512);    // P*128 f32 = P*512 B
    short* q2 = (short*)(big + (size_t)P * 512);       // P*256 i16 (aliases xbuf1)
    float* xbuf2 = (float*)(big + (size_t)P * 1024);   // P*256 f32 = P*1024 B
    float* xbuf3 = (float*)big;                        // P*512 f32 = P*2048 B

    const int* src = edge_index;
    const int* dst = edge_index + E;

    // setup: 4 weight quants + cnt zeroing (one launch)
    k_setup<<<676, 256, 0, stream>>>(W1, W1q, dsW1, W2, W2q, dsW2, W3, W3q, dsW3,
                                     Wfc, Wfcq, dsWfc, cnt, NV);

    // CSR build (parallel scan)
    k_count<<<(E + 255) / 256, 256, 0, stream>>>(dst, E, cnt);
    k_scan1<<<NB, 256, 0, stream>>>(cnt, dinv, NV, bsum);
    k_scan2<<<1, 256, 0, stream>>>(bsum, NB, offs, NV);
    k_scan3<<<NB, 256, 0, stream>>>(cnt, bsum, NV, offs, cursor);
    k_fill<<<(E + 255) / 256, 256, 0, stream>>>(src, dst, E, cursor, dinv, csr_pk);

    dim3 blk(256);
    dim3 blk512(512);
    const int qGrid = (NV + 3) / 4;    // rowquant: 4 rows/block
    const int aGrid = P / 16;          // agg: 16 nodes/block
    const int nbx = P / 128;           // 392

    // layer 1: quant(node) -> q01, agg -> A1q+dsAgg, i8 gemm -> xbuf1
    k_rowquant<128><<<qGrid, blk, 0, stream>>>(node, q01, dsQ, NV);
    k_agg_q<128><<<aGrid, blk, 0, stream>>>(q01, dsQ, offs, csr_pk, dinv, A1q, dsAgg, NV, P);
    k_gemm_i8<0><<<nbx * 1, blk512, 0, stream>>>(A1q, W1q, dsAgg, dsW1, b1, xbuf1, 128, 128, P, 1);

    // layer 2
    k_rowquant<128><<<qGrid, blk, 0, stream>>>(xbuf1, q01, dsQ, NV);
    k_agg_q<128><<<aGrid, blk, 0, stream>>>(q01, dsQ, offs, csr_pk, dinv, A1q, dsAgg, NV, P);
    k_gemm_i8<0><<<nbx * 2, blk512, 0, stream>>>(A1q, W2q, dsAgg, dsW2, b2, xbuf2, 256, 128, P, 2);

    // layer 3 (q2 aliases xbuf1 slot; xbuf3 overwrites the whole BIG region)
    k_rowquant<256><<<qGrid, blk, 0, stream>>>(xbuf2, q2, dsQ, NV);
    k_agg_q<256><<<aGrid, blk, 0, stream>>>(q2, dsQ, offs, csr_pk, dinv, A3q, dsAgg, NV, P);
    k_gemm_i8<0><<<nbx * 4, blk512, 0, stream>>>(A3q, W3q, dsAgg, dsW3, b3, xbuf3, 512, 256, P, 4);

    // FC: quantize xbuf3 rows -> A4q planes, then i8 gemm -> out (rows < NV)
    k_quant_i8<512><<<(P + 3) / 4, 256, 0, stream>>>(xbuf3, A4q, dsAfc, P);
    k_gemm_i8<2><<<nbx * 8, blk512, 0, stream>>>(A4q, Wfcq, dsAfc, dsWfc, bfc, out, 1024, 512, NV, 8);
}